// Round 3
// baseline (541.115 us; speedup 1.0000x reference)
//
#include <hip/hip_runtime.h>

#define T_N   1024
#define B_N   64
#define CIN   32
#define COUT  32
#define MODES 16
#define DT    0.01f
#define PI_F  3.14159265358979323846f

// ---------------------------------------------------------------------------
// Radix-2 Stockham FFT, length 1024, natural-order in/out, LDS ping-pong.
// Twiddles from a 512-entry LDS table: angle = SIGN*pi*(j<<s)/512.
// ---------------------------------------------------------------------------
template <int SIGN>
__device__ __forceinline__ void fft1024(float2* A, float2* B, const float2* TW, int tid) {
    float2* src = A;
    float2* dst = B;
    int m = 1;
#pragma unroll
    for (int s = 0; s < 10; ++s) {
        __syncthreads();
#pragma unroll
        for (int r = 0; r < 2; ++r) {
            int idx = tid + (r << 8);            // 0..511
            int k = idx & (m - 1);
            int j = idx >> s;
            float2 c0 = src[k + j * m];
            float2 c1 = src[k + j * m + 512];
            float2 w = TW[(j << s)];             // {cos, sin(SIGN*ang)}
            float ex = c0.x - c1.x, ey = c0.y - c1.y;
            dst[k + 2 * j * m]     = make_float2(c0.x + c1.x, c0.y + c1.y);
            dst[k + 2 * j * m + m] = make_float2(w.x * ex - w.y * ey, w.x * ey + w.y * ex);
        }
        float2* t = src; src = dst; dst = t;
        m <<= 1;
    }
    __syncthreads();
}

template <int SIGN>
__device__ __forceinline__ void build_tw(float2* TW, int tid) {
#pragma unroll
    for (int r = 0; r < 2; ++r) {
        int a = tid + (r << 8);
        float sn, cs;
        __sincosf((float)SIGN * PI_F * (float)a * (1.0f / 512.0f), &sn, &cs);
        TW[a] = make_float2(cs, sn);
    }
}

// ---------------------------------------------------------------------------
// forward FFT of each (b,i) row of x -> alpha[(b*CIN+i)][x]
// ---------------------------------------------------------------------------
__global__ __launch_bounds__(256) void k_fft_fwd(const float* __restrict__ x,
                                                 float2* __restrict__ alpha) {
    __shared__ float2 A[1024];
    __shared__ float2 Bb[1024];
    __shared__ float2 TW[512];
    int row = blockIdx.x;
    int tid = threadIdx.x;
    build_tw<-1>(TW, tid);
    const float* xr = x + (size_t)row * T_N;
#pragma unroll
    for (int r = 0; r < 4; ++r) {
        int j = tid + (r << 8);
        A[j] = make_float2(xr[j], 0.0f);
    }
    fft1024<-1>(A, Bb, TW, tid);
    float2* outp = alpha + (size_t)row * T_N;
#pragma unroll
    for (int r = 0; r < 4; ++r) {
        int j = tid + (r << 8);
        outp[j] = A[j];
    }
}

// ---------------------------------------------------------------------------
// transpose alpha[(b*CIN+i)][x] -> alphaT[i][x][b]
// ---------------------------------------------------------------------------
__global__ __launch_bounds__(256) void k_transpose_a(const float2* __restrict__ alpha,
                                                     float2* __restrict__ alphaT) {
    __shared__ float2 T[32 * 66];
    int blk = blockIdx.x;
    int i = blk >> 5, xt = blk & 31;
    int tid = threadIdx.x;
#pragma unroll
    for (int r = 0; r < 8; ++r) {
        int e = tid + (r << 8);
        int xx = e & 31, b = e >> 5;
        T[xx * 66 + b] = alpha[((size_t)(b * CIN + i)) * T_N + xt * 32 + xx];
    }
    __syncthreads();
#pragma unroll
    for (int r = 0; r < 8; ++r) {
        int e = tid + (r << 8);
        int b = e & 63, xx = e >> 6;
        alphaT[((size_t)i * T_N + xt * 32 + xx) * B_N + b] = T[xx * 66 + b];
    }
}

// ---------------------------------------------------------------------------
// out1: per-frequency mixing; writes out1tmp[x][b*COUT+o] (coalesced).
// SoA alpha staging, b128 MAC reads.
// ---------------------------------------------------------------------------
__global__ __launch_bounds__(256) void k_out1(const float4* __restrict__ alphaT4,
                                              const float* __restrict__ pr,
                                              const float* __restrict__ pim,
                                              const float* __restrict__ rr,
                                              const float* __restrict__ ri,
                                              float2* __restrict__ out1tmp) {
    __shared__ float sARe[32 * 64];   // [i][b]
    __shared__ float sAIm[32 * 64];
    __shared__ float2 Hs[32 * 32];    // [i][o]
    int x = blockIdx.x;
    int tid = threadIdx.x;

    // stage alpha slice (all i, all b) for this x
#pragma unroll
    for (int r = 0; r < 4; ++r) {
        int e = tid + (r << 8);          // 0..1023: i = e>>5, bp = e&31
        int i = e >> 5, bp = e & 31;
        float4 v = alphaT4[((size_t)i * T_N + x) * (B_N / 2) + bp];
        *(float2*)&sARe[i * 64 + bp * 2] = make_float2(v.x, v.z);
        *(float2*)&sAIm[i * 64 + bp * 2] = make_float2(v.y, v.w);
    }

    int fx = x - ((x >= 512) ? 1024 : 0);
    float w = (float)fx * (2.0f * PI_F / (T_N * DT));
#pragma unroll
    for (int r = 0; r < 4; ++r) {
        int e = tid + (r << 8);
        int i = e >> 5, o = e & 31;
        int base = (i * COUT + o) * MODES;
        float hr = 0.f, hi = 0.f;
#pragma unroll
        for (int k = 0; k < MODES; ++k) {
            float a = pr[base + k], bI = pim[base + k];
            float d = w - bI;
            float inv = 1.0f / (a * a + d * d);
            float vR = -a * inv, vI = -d * inv;
            float sR = rr[base + k], sI = ri[base + k];
            hr += sR * vR - sI * vI;
            hi += sR * vI + sI * vR;
        }
        Hs[i * 32 + o] = make_float2(hr, hi);
    }
    __syncthreads();

    int o = tid & 31, bg = tid >> 5;     // 8 b per thread
    float accR[8] = {}, accI[8] = {};
#pragma unroll 2
    for (int i = 0; i < CIN; ++i) {
        float2 h = Hs[i * 32 + o];
        float4 ar0 = *(const float4*)&sARe[i * 64 + bg * 8];
        float4 ar1 = *(const float4*)&sARe[i * 64 + bg * 8 + 4];
        float4 ai0 = *(const float4*)&sAIm[i * 64 + bg * 8];
        float4 ai1 = *(const float4*)&sAIm[i * 64 + bg * 8 + 4];
        float aR[8] = {ar0.x, ar0.y, ar0.z, ar0.w, ar1.x, ar1.y, ar1.z, ar1.w};
        float aI[8] = {ai0.x, ai0.y, ai0.z, ai0.w, ai1.x, ai1.y, ai1.z, ai1.w};
#pragma unroll
        for (int bb = 0; bb < 8; ++bb) {
            accR[bb] += aR[bb] * h.x - aI[bb] * h.y;
            accI[bb] += aR[bb] * h.y + aI[bb] * h.x;
        }
    }
#pragma unroll
    for (int bb = 0; bb < 8; ++bb) {
        out1tmp[(size_t)x * 2048 + (bg * 8 + bb) * 32 + o] =
            make_float2(accR[bb], accI[bb]);
    }
}

// ---------------------------------------------------------------------------
// out2 v3: grid = (i:32) x (o:32) x (xh:2) = 2048 blocks. 4 waves split the
// x-subtile; SoA LDS planes; per-chunk partials (no atomics).
// partial[chunk=(i*2+xh)][b][o][k]
// ---------------------------------------------------------------------------
__global__ __launch_bounds__(256) void k_out2(const float4* __restrict__ alphaT4,
                                              const float* __restrict__ pr,
                                              const float* __restrict__ pim,
                                              const float* __restrict__ rr,
                                              const float* __restrict__ ri,
                                              float2* __restrict__ partial) {
    __shared__ float sA[2][2048];     // [re/im][xx(32)][b(64)]
    __shared__ float sV[2][512];      // [re/im][xx(32)][k(16)]
    __shared__ float sPol[4][16];     // pr, pim, rr, ri for (i,o,:)

    int blk = blockIdx.x;
    int i = blk >> 6, o = (blk >> 1) & 31, xh = blk & 1;
    int tid = threadIdx.x;
    int xg = tid >> 6, lane = tid & 63;
    int bq = lane & 15, kq = lane >> 4;

    if (tid < 16) {
        int pidx = (i * COUT + o) * MODES + tid;
        sPol[0][tid] = pr[pidx]; sPol[1][tid] = pim[pidx];
        sPol[2][tid] = rr[pidx]; sPol[3][tid] = ri[pidx];
    }

    float accR[4][4] = {}, accI[4][4] = {};
    const float w_scale = 2.0f * PI_F / (T_N * DT);

    for (int xt = 0; xt < 16; ++xt) {
        int x0 = xh * 512 + xt * 32;
        __syncthreads();
        // stage A tile [32 xx][64 b], SoA deinterleave (1024 float4 = 16 KB)
        const float4* src = alphaT4 + ((size_t)i * T_N + x0) * (B_N / 2);
#pragma unroll
        for (int r = 0; r < 4; ++r) {
            int e = tid + (r << 8);          // xx = e>>5, bp = e&31
            float4 v = src[e];
            int xx = e >> 5, bp = e & 31;
            *(float2*)&sA[0][xx * 64 + bp * 2] = make_float2(v.x, v.z);
            *(float2*)&sA[1][xx * 64 + bp * 2] = make_float2(v.y, v.w);
        }
        // V table: v[xx][k] = -res/(i*w - pole)
#pragma unroll
        for (int r = 0; r < 2; ++r) {
            int e = tid + (r << 8);          // 0..511: xx = e>>4, k = e&15
            int k = e & 15, xx = e >> 4;
            int xgl = x0 + xx;
            int fx = xgl - ((xgl >= 512) ? 1024 : 0);
            float w = (float)fx * w_scale;
            float a = sPol[0][k], bI = sPol[1][k];
            float d = w - bI;
            float inv = 1.0f / (a * a + d * d);
            float uR = -a * inv, uI = -d * inv;
            float sR = sPol[2][k], sI = sPol[3][k];
            sV[0][e] = -(sR * uR - sI * uI);
            sV[1][e] = -(sR * uI + sI * uR);
        }
        __syncthreads();

        // MAC: this wave handles xx in [xg*8, xg*8+8)
#pragma unroll
        for (int q = 0; q < 8; ++q) {
            int xx = xg * 8 + q;
            float4 ar = *(const float4*)&sA[0][xx * 64 + bq * 4];
            float4 ai = *(const float4*)&sA[1][xx * 64 + bq * 4];
            float4 vr = *(const float4*)&sV[0][xx * 16 + kq * 4];
            float4 vi = *(const float4*)&sV[1][xx * 16 + kq * 4];
            float aR[4] = {ar.x, ar.y, ar.z, ar.w};
            float aI[4] = {ai.x, ai.y, ai.z, ai.w};
            float vR[4] = {vr.x, vr.y, vr.z, vr.w};
            float vI[4] = {vi.x, vi.y, vi.z, vi.w};
#pragma unroll
            for (int b_ = 0; b_ < 4; ++b_)
#pragma unroll
                for (int k_ = 0; k_ < 4; ++k_) {
                    accR[b_][k_] += aR[b_] * vR[k_] - aI[b_] * vI[k_];
                    accI[b_][k_] += aR[b_] * vI[k_] + aI[b_] * vR[k_];
                }
        }
    }

    // cross-wave reduction into wave 0 (reuse sA as 4096-float scratch)
    float* red = &sA[0][0];
    __syncthreads();
    if (xg >= 2) {
        int base = (xg - 2) * 2048;
#pragma unroll
        for (int b_ = 0; b_ < 4; ++b_)
#pragma unroll
            for (int k_ = 0; k_ < 4; ++k_) {
                int f = b_ * 4 + k_;
                red[base + f * 64 + lane] = accR[b_][k_];
                red[base + (f + 16) * 64 + lane] = accI[b_][k_];
            }
    }
    __syncthreads();
    if (xg < 2) {
        int base = xg * 2048;
#pragma unroll
        for (int b_ = 0; b_ < 4; ++b_)
#pragma unroll
            for (int k_ = 0; k_ < 4; ++k_) {
                int f = b_ * 4 + k_;
                accR[b_][k_] += red[base + f * 64 + lane];
                accI[b_][k_] += red[base + (f + 16) * 64 + lane];
            }
    }
    __syncthreads();
    if (xg == 1) {
#pragma unroll
        for (int b_ = 0; b_ < 4; ++b_)
#pragma unroll
            for (int k_ = 0; k_ < 4; ++k_) {
                int f = b_ * 4 + k_;
                red[f * 64 + lane] = accR[b_][k_];
                red[(f + 16) * 64 + lane] = accI[b_][k_];
            }
    }
    __syncthreads();
    if (xg == 0) {
        int chunk = i * 2 + xh;
        float2* dst = partial + (size_t)chunk * (B_N * COUT * MODES);
#pragma unroll
        for (int b_ = 0; b_ < 4; ++b_) {
#pragma unroll
            for (int k_ = 0; k_ < 4; ++k_) {
                int f = b_ * 4 + k_;
                accR[b_][k_] += red[f * 64 + lane];
                accI[b_][k_] += red[(f + 16) * 64 + lane];
            }
            int b = bq * 4 + b_;
            float4 w0 = make_float4(accR[b_][0], accI[b_][0], accR[b_][1], accI[b_][1]);
            float4 w1 = make_float4(accR[b_][2], accI[b_][2], accR[b_][3], accI[b_][3]);
            float4* p = (float4*)(dst + ((b * COUT + o) * MODES + kq * 4));
            p[0] = w0; p[1] = w1;
        }
    }
}

// ---------------------------------------------------------------------------
// reduce 64 chunks of partial into o2[b][o][k]
// ---------------------------------------------------------------------------
__global__ __launch_bounds__(256) void k_reduce(const float4* __restrict__ p,
                                                float4* __restrict__ o2) {
    int f = blockIdx.x * 256 + threadIdx.x;   // 16384 float4s
    float4 s = make_float4(0.f, 0.f, 0.f, 0.f);
#pragma unroll 4
    for (int c = 0; c < 64; ++c) {
        float4 v = p[(size_t)c * 16384 + f];
        s.x += v.x; s.y += v.y; s.z += v.z; s.w += v.w;
    }
    o2[f] = s;
}

// ---------------------------------------------------------------------------
// transpose out1tmp[x][bo] -> out1T[bo][x]
// ---------------------------------------------------------------------------
__global__ __launch_bounds__(256) void k_transpose_o1(const float2* __restrict__ out1tmp,
                                                      float2* __restrict__ out1T) {
    __shared__ float2 T[64 * 33];
    int blk = blockIdx.x;
    int bot = blk >> 5, xt = blk & 31;
    int tid = threadIdx.x;
#pragma unroll
    for (int r = 0; r < 8; ++r) {
        int e = tid + (r << 8);
        int j = e & 63, xr = e >> 6;
        T[j * 33 + xr] = out1tmp[((size_t)(xt * 32 + xr)) * 2048 + bot * 64 + j];
    }
    __syncthreads();
#pragma unroll
    for (int r = 0; r < 8; ++r) {
        int e = tid + (r << 8);
        int xx = e & 31, j = e >> 5;
        out1T[((size_t)(bot * 64 + j)) * T_N + xt * 32 + xx] = T[j * 33 + xx];
    }
}

// ---------------------------------------------------------------------------
// x1 = Re(ifft(out1)) per (b,o) row; writes d_out fully.
// ---------------------------------------------------------------------------
__global__ __launch_bounds__(256) void k_ifft(const float2* __restrict__ out1T,
                                              float* __restrict__ outp) {
    __shared__ float2 A[1024];
    __shared__ float2 Bb[1024];
    __shared__ float2 TW[512];
    int row = blockIdx.x;
    int tid = threadIdx.x;
    build_tw<1>(TW, tid);
    const float2* src = out1T + (size_t)row * T_N;
#pragma unroll
    for (int r = 0; r < 4; ++r) {
        int j = tid + (r << 8);
        A[j] = src[j];
    }
    fft1024<1>(A, Bb, TW, tid);
    float* dst = outp + (size_t)row * T_N;
    const float inv_n = 1.0f / (float)T_N;
#pragma unroll
    for (int r = 0; r < 4; ++r) {
        int j = tid + (r << 8);
        dst[j] = A[j].x * inv_n;
    }
}

// ---------------------------------------------------------------------------
// x2 v3: block = (o, zt of 64 z). SoA padded LDS planes (row stride 76).
// Thread owns 4b x 4z; zq = tid&15 (coalesced output), bq = tid>>4.
// ---------------------------------------------------------------------------
#define XROW 76
__global__ __launch_bounds__(256) void k_x2(const float2* __restrict__ o2,
                                            const float* __restrict__ pr,
                                            const float* __restrict__ pim,
                                            float* __restrict__ outp) {
    __shared__ float sPRe[32 * XROW], sPIm[32 * XROW];   // [j][b]
    __shared__ float sERe[32 * XROW], sEIm[32 * XROW];   // [j][z]
    __shared__ float s_pr[512], s_pim[512];
    int blk = blockIdx.x;
    int o = blk >> 4, zt = blk & 15;
    int tid = threadIdx.x;
    int zq = tid & 15, bq = tid >> 4;

#pragma unroll
    for (int r = 0; r < 2; ++r) {
        int e = tid + (r << 8);
        int c = e >> 4, m = e & 15;
        int pidx = (c * COUT + o) * MODES + m;
        s_pr[e] = pr[pidx];
        s_pim[e] = pim[pidx];
    }

    float acc[4][4] = {};

    for (int ct = 0; ct < 16; ++ct) {
        int cm0 = ct * 32;
        __syncthreads();
        // stage P tile: coalesced global read, SoA LDS write
#pragma unroll
        for (int r = 0; r < 8; ++r) {
            int e = tid + (r << 8);          // j = e&31, b = e>>5
            int j = e & 31, b = e >> 5;
            float2 v = o2[b * 512 + cm0 + j];
            sPRe[j * XROW + b] = v.x;
            sPIm[j * XROW + b] = v.y;
        }
        // E tile: exp(pole*t)
#pragma unroll
        for (int r = 0; r < 8; ++r) {
            int e = tid + (r << 8);          // z = e&63, j = e>>6
            int z = e & 63, j = e >> 6;
            int cm = cm0 + j;
            float tz = (float)(zt * 64 + z) * DT;
            float er = __expf(s_pr[cm] * tz);
            float sn, cn;
            __sincosf(s_pim[cm] * tz, &sn, &cn);
            sERe[j * XROW + z] = er * cn;
            sEIm[j * XROW + z] = er * sn;
        }
        __syncthreads();

#pragma unroll 2
        for (int j = 0; j < 32; ++j) {
            float4 p0 = *(const float4*)&sPRe[j * XROW + bq * 4];
            float4 p1 = *(const float4*)&sPIm[j * XROW + bq * 4];
            float4 e0 = *(const float4*)&sERe[j * XROW + zq * 4];
            float4 e1 = *(const float4*)&sEIm[j * XROW + zq * 4];
            float PRe[4] = {p0.x, p0.y, p0.z, p0.w};
            float PIm[4] = {p1.x, p1.y, p1.z, p1.w};
            float ERe[4] = {e0.x, e0.y, e0.z, e0.w};
            float EIm[4] = {e1.x, e1.y, e1.z, e1.w};
#pragma unroll
            for (int b_ = 0; b_ < 4; ++b_)
#pragma unroll
                for (int z_ = 0; z_ < 4; ++z_) {
                    acc[b_][z_] += PRe[b_] * ERe[z_] - PIm[b_] * EIm[z_];
                }
        }
    }

    const float inv_n = 1.0f / (float)T_N;
#pragma unroll
    for (int b_ = 0; b_ < 4; ++b_) {
        size_t idx = (size_t)(bq * 4 + b_) * (COUT * T_N) + (size_t)o * T_N + zt * 64 + zq * 4;
        float4* p = (float4*)(outp + idx);
        float4 v = *p;
        v.x += acc[b_][0] * inv_n;
        v.y += acc[b_][1] * inv_n;
        v.z += acc[b_][2] * inv_n;
        v.w += acc[b_][3] * inv_n;
        *p = v;
    }
}

// ---------------------------------------------------------------------------
extern "C" void kernel_launch(void* const* d_in, const int* in_sizes, int n_in,
                              void* d_out, int out_size, void* d_ws, size_t ws_size,
                              hipStream_t stream) {
    const float* x   = (const float*)d_in[0];
    const float* pr  = (const float*)d_in[2];
    const float* pim = (const float*)d_in[3];
    const float* rr  = (const float*)d_in[4];
    const float* ri  = (const float*)d_in[5];
    float* outp = (float*)d_out;

    char* ws = (char*)d_ws;
    const size_t RA = (size_t)B_N * CIN * T_N * sizeof(float2);  // 16 MB
    float2* alpha   = (float2*)ws;                 // region A
    float2* alphaT  = (float2*)(ws + RA);          // region B
    float2* o2      = (float2*)(ws + 2 * RA);      // 256 KB
    float2* partial = (float2*)ws;                 // region A reuse (alpha dead)
    float2* out1tmp = (float2*)ws;                 // region A reuse (partial dead)
    float2* out1T   = (float2*)(ws + RA);          // region B reuse (alphaT dead)

    k_fft_fwd     <<<B_N * CIN, 256, 0, stream>>>(x, alpha);
    k_transpose_a <<<CIN * 32, 256, 0, stream>>>(alpha, alphaT);
    k_out2        <<<CIN * COUT * 2, 256, 0, stream>>>((const float4*)alphaT,
                                                       pr, pim, rr, ri, partial);
    k_reduce      <<<64, 256, 0, stream>>>((const float4*)partial, (float4*)o2);
    k_out1        <<<T_N, 256, 0, stream>>>((const float4*)alphaT,
                                            pr, pim, rr, ri, out1tmp);
    k_transpose_o1<<<32 * 32, 256, 0, stream>>>(out1tmp, out1T);
    k_ifft        <<<B_N * COUT, 256, 0, stream>>>(out1T, outp);
    k_x2          <<<COUT * (T_N / 64), 256, 0, stream>>>(o2, pr, pim, outp);
}

// Round 5
// 483.065 us; speedup vs baseline: 1.1202x; 1.1202x over previous
//
#include <hip/hip_runtime.h>

#define T_N   1024
#define B_N   64
#define CIN   32
#define COUT  32
#define MODES 16
#define DT    0.01f
#define PI_F  3.14159265358979323846f
#define W_SCALE 0.613592315154256f   /* 2*pi/(T_N*DT) */
#define W_NYQ  (-314.1592653589793f) /* -pi/DT */

// ---------------------------------------------------------------------------
// Radix-2 Stockham FFT, length 1024, LDS twiddle table.
// ---------------------------------------------------------------------------
template <int SIGN>
__device__ __forceinline__ void fft1024(float2* A, float2* B, const float2* TW, int tid) {
    float2* src = A;
    float2* dst = B;
    int m = 1;
#pragma unroll
    for (int s = 0; s < 10; ++s) {
        __syncthreads();
#pragma unroll
        for (int r = 0; r < 2; ++r) {
            int idx = tid + (r << 8);
            int k = idx & (m - 1);
            int j = idx >> s;
            float2 c0 = src[k + j * m];
            float2 c1 = src[k + j * m + 512];
            float2 w = TW[(j << s)];
            float ex = c0.x - c1.x, ey = c0.y - c1.y;
            dst[k + 2 * j * m]     = make_float2(c0.x + c1.x, c0.y + c1.y);
            dst[k + 2 * j * m + m] = make_float2(w.x * ex - w.y * ey, w.x * ey + w.y * ex);
        }
        float2* t = src; src = dst; dst = t;
        m <<= 1;
    }
    __syncthreads();
}

template <int SIGN>
__device__ __forceinline__ void build_tw(float2* TW, int tid) {
#pragma unroll
    for (int r = 0; r < 2; ++r) {
        int a = tid + (r << 8);
        float sn, cs;
        __sincosf((float)SIGN * PI_F * (float)a * (1.0f / 512.0f), &sn, &cs);
        TW[a] = make_float2(cs, sn);
    }
}

__global__ __launch_bounds__(256) void k_fft_fwd(const float* __restrict__ x,
                                                 float2* __restrict__ alpha) {
    __shared__ float2 A[1024];
    __shared__ float2 Bb[1024];
    __shared__ float2 TW[512];
    int row = blockIdx.x;
    int tid = threadIdx.x;
    build_tw<-1>(TW, tid);
    const float* xr = x + (size_t)row * T_N;
#pragma unroll
    for (int r = 0; r < 4; ++r) {
        int j = tid + (r << 8);
        A[j] = make_float2(xr[j], 0.0f);
    }
    fft1024<-1>(A, Bb, TW, tid);
    float2* outp = alpha + (size_t)row * T_N;
#pragma unroll
    for (int r = 0; r < 4; ++r) {
        int j = tid + (r << 8);
        outp[j] = A[j];
    }
}

// ---------------------------------------------------------------------------
// transpose alpha[(b*CIN+i)][x] -> alphaT[i][x][b]
// ---------------------------------------------------------------------------
__global__ __launch_bounds__(256) void k_transpose_a(const float2* __restrict__ alpha,
                                                     float2* __restrict__ alphaT) {
    __shared__ float2 T[32 * 66];
    int blk = blockIdx.x;
    int i = blk >> 5, xt = blk & 31;
    int tid = threadIdx.x;
#pragma unroll
    for (int r = 0; r < 8; ++r) {
        int e = tid + (r << 8);
        int xx = e & 31, b = e >> 5;
        T[xx * 66 + b] = alpha[((size_t)(b * CIN + i)) * T_N + xt * 32 + xx];
    }
    __syncthreads();
#pragma unroll
    for (int r = 0; r < 8; ++r) {
        int e = tid + (r << 8);
        int b = e & 63, xx = e >> 6;
        alphaT[((size_t)i * T_N + xt * 32 + xx) * B_N + b] = T[xx * 66 + b];
    }
}

// ---------------------------------------------------------------------------
// out1: per-frequency mixing (unchanged — works).
// ---------------------------------------------------------------------------
__global__ __launch_bounds__(256) void k_out1(const float4* __restrict__ alphaT4,
                                              const float* __restrict__ pr,
                                              const float* __restrict__ pim,
                                              const float* __restrict__ rr,
                                              const float* __restrict__ ri,
                                              float2* __restrict__ out1tmp) {
    __shared__ float sARe[32 * 64];
    __shared__ float sAIm[32 * 64];
    __shared__ float2 Hs[32 * 32];
    int x = blockIdx.x;
    int tid = threadIdx.x;

#pragma unroll
    for (int r = 0; r < 4; ++r) {
        int e = tid + (r << 8);
        int i = e >> 5, bp = e & 31;
        float4 v = alphaT4[((size_t)i * T_N + x) * (B_N / 2) + bp];
        *(float2*)&sARe[i * 64 + bp * 2] = make_float2(v.x, v.z);
        *(float2*)&sAIm[i * 64 + bp * 2] = make_float2(v.y, v.w);
    }

    int fx = x - ((x >= 512) ? 1024 : 0);
    float w = (float)fx * W_SCALE;
#pragma unroll
    for (int r = 0; r < 4; ++r) {
        int e = tid + (r << 8);
        int i = e >> 5, o = e & 31;
        int base = (i * COUT + o) * MODES;
        float hr = 0.f, hi = 0.f;
#pragma unroll
        for (int k = 0; k < MODES; ++k) {
            float a = pr[base + k], bI = pim[base + k];
            float d = w - bI;
            float inv = 1.0f / (a * a + d * d);
            float vR = -a * inv, vI = -d * inv;
            float sR = rr[base + k], sI = ri[base + k];
            hr += sR * vR - sI * vI;
            hi += sR * vI + sI * vR;
        }
        Hs[i * 32 + o] = make_float2(hr, hi);
    }
    __syncthreads();

    int o = tid & 31, bg = tid >> 5;
    float accR[8] = {}, accI[8] = {};
#pragma unroll 2
    for (int i = 0; i < CIN; ++i) {
        float2 h = Hs[i * 32 + o];
        float4 ar0 = *(const float4*)&sARe[i * 64 + bg * 8];
        float4 ar1 = *(const float4*)&sARe[i * 64 + bg * 8 + 4];
        float4 ai0 = *(const float4*)&sAIm[i * 64 + bg * 8];
        float4 ai1 = *(const float4*)&sAIm[i * 64 + bg * 8 + 4];
        float aR[8] = {ar0.x, ar0.y, ar0.z, ar0.w, ar1.x, ar1.y, ar1.z, ar1.w};
        float aI[8] = {ai0.x, ai0.y, ai0.z, ai0.w, ai1.x, ai1.y, ai1.z, ai1.w};
#pragma unroll
        for (int bb = 0; bb < 8; ++bb) {
            accR[bb] += aR[bb] * h.x - aI[bb] * h.y;
            accI[bb] += aR[bb] * h.y + aI[bb] * h.x;
        }
    }
#pragma unroll
    for (int bb = 0; bb < 8; ++bb) {
        out1tmp[(size_t)x * 2048 + (bg * 8 + bb) * 32 + o] =
            make_float2(accR[bb], accI[bb]);
    }
}

// ---------------------------------------------------------------------------
// out2 v4 (conjugate-folded): out2[b,o,k] = sum_i sum_{x=0..511} aR*C1 + aI*C2
// C1 = 2*p*r/(p^2+w^2), C2 = -2*w*r/(p^2+w^2)  (minus of out2 folded in).
// x=0 column: aI slot carries Re(alpha[512]); C1 = r/p, C2 = -r/(i*w_nyq - p).
// grid = dim3(xq_n, 8 og, 32 i), 128 threads. Thread tile 8b x 4nk.
// ---------------------------------------------------------------------------
#define AROW 164
#define VROW 324
__global__ __launch_bounds__(128, 2) void k_out2(const float4* __restrict__ alphaT4,
                                                 const float* __restrict__ pr,
                                                 const float* __restrict__ pim,
                                                 const float* __restrict__ rr,
                                                 const float* __restrict__ ri,
                                                 float2* __restrict__ partial) {
    __shared__ __align__(16) float sA[8 * AROW];     // [xx][8 grp][16+4 fl]
    __shared__ __align__(16) float sV[8 * VROW];     // [xx][16 grp][16+4 fl]
    __shared__ float sPol[4][64];

    const int xq = blockIdx.x, og = blockIdx.y, i = blockIdx.z;
    const int K_xx = 512 / gridDim.x;
    const int nt = K_xx >> 3;
    const int xbase = xq * K_xx;
    const int tid = threadIdx.x;
    const int bq = tid & 7, kq = tid >> 3;

    if (tid < 64) {
        int oo = tid >> 4, k = tid & 15;
        int pidx = (i * COUT + og * 4 + oo) * MODES + k;
        sPol[0][tid] = pr[pidx]; sPol[1][tid] = pim[pidx];
        sPol[2][tid] = rr[pidx]; sPol[3][tid] = ri[pidx];
    }
    __syncthreads();

    float accR[8][4] = {}, accI[8][4] = {};

    for (int t = 0; t < nt; ++t) {
        int x0 = xbase + t * 8;
        // stage alpha tile [8 xx][64 b] into padded layout (FIX: e>>5 / e&31)
        const float4* src = alphaT4 + ((size_t)i * T_N + x0) * (B_N / 2);
#pragma unroll
        for (int r = 0; r < 2; ++r) {
            int e = tid + (r << 7);              // 0..255: xx=e>>5, bp=e&31
            int xx = e >> 5, bp = e & 31;
            *(float4*)&sA[xx * AROW + (bp >> 2) * 20 + (bp & 3) * 4] = src[e];
        }
        // V table: [8 xx][64 nk] -> f4 (C1re,C1im,C2re,C2im)
#pragma unroll
        for (int r = 0; r < 4; ++r) {
            int e = tid + (r << 7);              // 0..511: xx=e>>6, nk=e&63
            int xx = e >> 6, nk = e & 63;
            int xg = x0 + xx;
            float a = sPol[0][nk], bI = sPol[1][nk];
            float sR = sPol[2][nk], sI = sPol[3][nk];
            float c1r, c1i, c2r, c2i;
            if (xg == 0) {
                float s1 = a * a + bI * bI;
                float q1r = a / s1, q1i = -bI / s1;
                c1r = sR * q1r - sI * q1i;
                c1i = sR * q1i + sI * q1r;
                float dr = -a, di = W_NYQ - bI;
                float s2 = dr * dr + di * di;
                float q2r = dr / s2, q2i = -di / s2;
                c2r = -(sR * q2r - sI * q2i);
                c2i = -(sR * q2i + sI * q2r);
            } else {
                float w = (float)xg * W_SCALE;
                float denr = a * a - bI * bI + w * w;
                float deni = 2.0f * a * bI;
                float s = denr * denr + deni * deni;
                float qr = denr / s, qi = -deni / s;
                float prr = a * sR - bI * sI;
                float pri = a * sI + bI * sR;
                c1r = 2.0f * (prr * qr - pri * qi);
                c1i = 2.0f * (prr * qi + pri * qr);
                float rqr = sR * qr - sI * qi;
                float rqi = sR * qi + sI * qr;
                c2r = -2.0f * w * rqr;
                c2i = -2.0f * w * rqi;
            }
            *(float4*)&sV[xx * VROW + (nk >> 2) * 20 + (nk & 3) * 4] =
                make_float4(c1r, c1i, c2r, c2i);
        }
        __syncthreads();
        if (xq == 0 && t == 0) {
            // patch col x=0: imag slot <- Re(alpha[b,i,512])
            if (tid < 16) {
                float4 v = alphaT4[((size_t)i * T_N + 512) * (B_N / 2) + tid];
                int b0 = tid * 2;
                sA[(b0 >> 3) * 20 + (b0 & 7) * 2 + 1] = v.x;
                int b1 = b0 + 1;
                sA[(b1 >> 3) * 20 + (b1 & 7) * 2 + 1] = v.z;
            }
            __syncthreads();
        }

        // MAC
#pragma unroll
        for (int xx = 0; xx < 8; ++xx) {
            const float* ap = &sA[xx * AROW + bq * 20];
            float4 a0 = *(const float4*)&ap[0];
            float4 a1 = *(const float4*)&ap[4];
            float4 a2 = *(const float4*)&ap[8];
            float4 a3 = *(const float4*)&ap[12];
            const float* vp = &sV[xx * VROW + kq * 20];
            float4 v0 = *(const float4*)&vp[0];
            float4 v1 = *(const float4*)&vp[4];
            float4 v2 = *(const float4*)&vp[8];
            float4 v3 = *(const float4*)&vp[12];
            float aR[8] = {a0.x, a0.z, a1.x, a1.z, a2.x, a2.z, a3.x, a3.z};
            float aI[8] = {a0.y, a0.w, a1.y, a1.w, a2.y, a2.w, a3.y, a3.w};
            float C1r[4] = {v0.x, v1.x, v2.x, v3.x};
            float C1i[4] = {v0.y, v1.y, v2.y, v3.y};
            float C2r[4] = {v0.z, v1.z, v2.z, v3.z};
            float C2i[4] = {v0.w, v1.w, v2.w, v3.w};
#pragma unroll
            for (int bb = 0; bb < 8; ++bb)
#pragma unroll
                for (int kk = 0; kk < 4; ++kk) {
                    accR[bb][kk] += aR[bb] * C1r[kk] + aI[bb] * C2r[kk];
                    accI[bb][kk] += aR[bb] * C1i[kk] + aI[bb] * C2i[kk];
                }
        }
        __syncthreads();
    }

    int chunk = i * gridDim.x + xq;
    float4* dst = (float4*)(partial + (size_t)chunk * (B_N * 512));
#pragma unroll
    for (int bb = 0; bb < 8; ++bb) {
        int b = bq * 8 + bb;
        int f4i = (b * 512 + og * 64 + kq * 4) >> 1;
        dst[f4i]     = make_float4(accR[bb][0], accI[bb][0], accR[bb][1], accI[bb][1]);
        dst[f4i + 1] = make_float4(accR[bb][2], accI[bb][2], accR[bb][3], accI[bb][3]);
    }
}

// ---------------------------------------------------------------------------
// reduce nchunk partials into o2[b][nk]
// ---------------------------------------------------------------------------
__global__ __launch_bounds__(256) void k_reduce(const float4* __restrict__ p,
                                                float4* __restrict__ o2, int nchunk) {
    int f = blockIdx.x * 256 + threadIdx.x;   // 16384 float4s
    float4 s = make_float4(0.f, 0.f, 0.f, 0.f);
    for (int c = 0; c < nchunk; ++c) {
        float4 v = p[(size_t)c * 16384 + f];
        s.x += v.x; s.y += v.y; s.z += v.z; s.w += v.w;
    }
    o2[f] = s;
}

// ---------------------------------------------------------------------------
// transpose out1tmp[x][bo] -> out1T[bo][x]
// ---------------------------------------------------------------------------
__global__ __launch_bounds__(256) void k_transpose_o1(const float2* __restrict__ out1tmp,
                                                      float2* __restrict__ out1T) {
    __shared__ float2 T[64 * 33];
    int blk = blockIdx.x;
    int bot = blk >> 5, xt = blk & 31;
    int tid = threadIdx.x;
#pragma unroll
    for (int r = 0; r < 8; ++r) {
        int e = tid + (r << 8);
        int j = e & 63, xr = e >> 6;
        T[j * 33 + xr] = out1tmp[((size_t)(xt * 32 + xr)) * 2048 + bot * 64 + j];
    }
    __syncthreads();
#pragma unroll
    for (int r = 0; r < 8; ++r) {
        int e = tid + (r << 8);
        int xx = e & 31, j = e >> 5;
        out1T[((size_t)(bot * 64 + j)) * T_N + xt * 32 + xx] = T[j * 33 + xx];
    }
}

__global__ __launch_bounds__(256) void k_ifft(const float2* __restrict__ out1T,
                                              float* __restrict__ outp) {
    __shared__ float2 A[1024];
    __shared__ float2 Bb[1024];
    __shared__ float2 TW[512];
    int row = blockIdx.x;
    int tid = threadIdx.x;
    build_tw<1>(TW, tid);
    const float2* src = out1T + (size_t)row * T_N;
#pragma unroll
    for (int r = 0; r < 4; ++r) {
        int j = tid + (r << 8);
        A[j] = src[j];
    }
    fft1024<1>(A, Bb, TW, tid);
    float* dst = outp + (size_t)row * T_N;
    const float inv_n = 1.0f / (float)T_N;
#pragma unroll
    for (int r = 0; r < 4; ++r) {
        int j = tid + (r << 8);
        dst[j] = A[j].x * inv_n;
    }
}

// ---------------------------------------------------------------------------
// x2 v4: grid dim3(cmh:4, zt:8, o:32), 256 thr. Thread 8b x 4z real acc.
// ---------------------------------------------------------------------------
#define PROW 100
#define EROW 132
__global__ __launch_bounds__(256, 4) void k_x2(const float4* __restrict__ o2f4,
                                               const float* __restrict__ pr,
                                               const float* __restrict__ pim,
                                               float* __restrict__ partial) {
    __shared__ __align__(16) float sPre[16 * PROW], sPim_[16 * PROW];
    __shared__ __align__(16) float sEre[16 * EROW], sEim[16 * EROW];
    __shared__ float s_pr[128], s_pim[128];

    const int cmh = blockIdx.x, zt = blockIdx.y, o = blockIdx.z;
    const int tid = threadIdx.x;
    const int zq = tid & 31, bq = tid >> 5;
    const int cmBase = cmh * 128;

    if (tid < 128) {
        int cm = cmBase + tid;
        int c = cm >> 4, m = cm & 15;
        int pidx = (c * COUT + o) * MODES + m;
        s_pr[tid] = pr[pidx];
        s_pim[tid] = pim[pidx];
    }

    float acc[8][4] = {};

    for (int t = 0; t < 8; ++t) {
        int cm0l = t * 16;
        __syncthreads();
        // stage P tile [16 j][64 b]  (FIX: o2 is 256 f4 per b; offset cm/2)
#pragma unroll
        for (int r = 0; r < 2; ++r) {
            int e = tid + (r << 8);              // 0..511: b=e>>3, jp=e&7
            int b = e >> 3, jp = e & 7;
            float4 v = o2f4[b * 256 + ((cmBase + cm0l) >> 1) + jp];
            int j0 = jp * 2;
            int pa = (b >> 3) * 12 + (b & 7);
            sPre[j0 * PROW + pa] = v.x;
            sPim_[j0 * PROW + pa] = v.y;
            sPre[(j0 + 1) * PROW + pa] = v.z;
            sPim_[(j0 + 1) * PROW + pa] = v.w;
        }
        // E tile [16 j][128 z]
#pragma unroll
        for (int r = 0; r < 8; ++r) {
            int e = tid + (r << 8);
            int z = e & 127, j = e >> 7;
            float gr = s_pr[cm0l + j], gi = s_pim[cm0l + j];
            float tz = (float)(zt * 128 + z) * DT;
            float er = __expf(gr * tz);
            float sn, cn;
            __sincosf(gi * tz, &sn, &cn);
            sEre[j * EROW + z] = er * cn;
            sEim[j * EROW + z] = er * sn;
        }
        __syncthreads();

#pragma unroll 4
        for (int j = 0; j < 16; ++j) {
            const float* pp = &sPre[j * PROW + bq * 12];
            const float* qq = &sPim_[j * PROW + bq * 12];
            float4 p0 = *(const float4*)&pp[0];
            float4 p1 = *(const float4*)&pp[4];
            float4 q0 = *(const float4*)&qq[0];
            float4 q1 = *(const float4*)&qq[4];
            float4 e0 = *(const float4*)&sEre[j * EROW + zq * 4];
            float4 e1 = *(const float4*)&sEim[j * EROW + zq * 4];
            float PRe[8] = {p0.x, p0.y, p0.z, p0.w, p1.x, p1.y, p1.z, p1.w};
            float PIm[8] = {q0.x, q0.y, q0.z, q0.w, q1.x, q1.y, q1.z, q1.w};
            float ERe[4] = {e0.x, e0.y, e0.z, e0.w};
            float EIm[4] = {e1.x, e1.y, e1.z, e1.w};
#pragma unroll
            for (int bb = 0; bb < 8; ++bb)
#pragma unroll
                for (int zz = 0; zz < 4; ++zz) {
                    acc[bb][zz] += PRe[bb] * ERe[zz] - PIm[bb] * EIm[zz];
                }
        }
    }

#pragma unroll
    for (int bb = 0; bb < 8; ++bb) {
        int b = bq * 8 + bb;
        size_t idx = (((size_t)cmh * B_N + b) * COUT + o) * T_N + zt * 128 + zq * 4;
        *(float4*)&partial[idx] = make_float4(acc[bb][0], acc[bb][1], acc[bb][2], acc[bb][3]);
    }
}

// ---------------------------------------------------------------------------
// x2 reduce: outp += (1/N) * sum_{cmh} partial   (FIX: 2048 blocks, stride 524288)
// ---------------------------------------------------------------------------
__global__ __launch_bounds__(256) void k_x2red(const float4* __restrict__ p,
                                               float4* __restrict__ outp) {
    int f = blockIdx.x * 256 + threadIdx.x;      // 0..524287 float4
    const float inv_n = 1.0f / (float)T_N;
    float4 s = make_float4(0.f, 0.f, 0.f, 0.f);
#pragma unroll
    for (int c = 0; c < 4; ++c) {
        float4 v = p[(size_t)c * 524288 + f];
        s.x += v.x; s.y += v.y; s.z += v.z; s.w += v.w;
    }
    float4 o = outp[f];
    o.x += s.x * inv_n; o.y += s.y * inv_n; o.z += s.z * inv_n; o.w += s.w * inv_n;
    outp[f] = o;
}

// ---------------------------------------------------------------------------
extern "C" void kernel_launch(void* const* d_in, const int* in_sizes, int n_in,
                              void* d_out, int out_size, void* d_ws, size_t ws_size,
                              hipStream_t stream) {
    const float* x   = (const float*)d_in[0];
    const float* pr  = (const float*)d_in[2];
    const float* pim = (const float*)d_in[3];
    const float* rr  = (const float*)d_in[4];
    const float* ri  = (const float*)d_in[5];
    float* outp = (float*)d_out;

    char* ws = (char*)d_ws;
    const size_t MB = 1024 * 1024;
    float2* alpha   = (float2*)ws;                     // [0,16M)
    float2* alphaT  = (float2*)(ws + 16 * MB);         // [16M,32M)
    float2* o2      = (float2*)(ws + 32 * MB);         // [32M,32.25M)

    int xq_n;
    float2* o2part;
    if (ws_size >= (size_t)(65 * MB)) {
        xq_n = 4;
        o2part = (float2*)(ws + 32 * MB + 256 * 1024);
    } else {
        xq_n = 2;
        o2part = (float2*)ws;                          // region A (alpha dead)
    }
    float2* out1tmp = (float2*)ws;                     // region A (after reduce)
    float2* out1T   = (float2*)(ws + 16 * MB);         // region B (alphaT dead)
    float*  x2part  = (float*)ws;                      // [0,32M) (A+B dead)

    k_fft_fwd     <<<B_N * CIN, 256, 0, stream>>>(x, alpha);
    k_transpose_a <<<CIN * 32, 256, 0, stream>>>(alpha, alphaT);
    k_out2        <<<dim3(xq_n, 8, 32), 128, 0, stream>>>((const float4*)alphaT,
                                                          pr, pim, rr, ri, o2part);
    k_reduce      <<<64, 256, 0, stream>>>((const float4*)o2part, (float4*)o2,
                                           32 * xq_n);
    k_out1        <<<T_N, 256, 0, stream>>>((const float4*)alphaT,
                                            pr, pim, rr, ri, out1tmp);
    k_transpose_o1<<<32 * 32, 256, 0, stream>>>(out1tmp, out1T);
    k_ifft        <<<B_N * COUT, 256, 0, stream>>>(out1T, outp);
    k_x2          <<<dim3(4, 8, 32), 256, 0, stream>>>((const float4*)o2,
                                                       pr, pim, x2part);
    k_x2red       <<<2048, 256, 0, stream>>>((const float4*)x2part, (float4*)outp);
}